// Round 2
// baseline (521.935 us; speedup 1.0000x reference)
//
#include <hip/hip_runtime.h>

// ExternalNeighbors: per-pair displacement + periodic shift + cutoff mask.
// Outputs (concatenated flat, all as float32):
//   [0*N .. 1*N) dist (0 if masked out)
//   [1*N .. 2*N) pair_first  (as float; -1 if masked out)
//   [2*N .. 3*N) pair_second (as float; -1 if masked out)
//   [3*N .. 6*N) paircoord (N,3) (0 if masked out)
//   [6*N .. 7*N) mask (1.0 / 0.0)

#define HARD_DIST_CUTOFF 2.0f

__global__ __launch_bounds__(256) void external_neighbors_kernel(
    const float* __restrict__ coords,       // n_real * 3 (flattened)
    const int*   __restrict__ real_atoms,   // n_real
    const int*   __restrict__ shifts,       // n_pairs * 3
    const float* __restrict__ cell,         // 9
    const int*   __restrict__ pair_first,   // n_pairs
    const int*   __restrict__ pair_second,  // n_pairs
    float* __restrict__ out,
    int n_pairs)
{
    // cell rows (broadcast scalar loads; L2-hit after first wave)
    const float c00 = cell[0], c01 = cell[1], c02 = cell[2];
    const float c10 = cell[3], c11 = cell[4], c12 = cell[5];
    const float c20 = cell[6], c21 = cell[7], c22 = cell[8];

    const size_t N = (size_t)n_pairs;
    float* __restrict__ out_dist = out;
    float* __restrict__ out_pf   = out + N;
    float* __restrict__ out_ps   = out + 2 * N;
    float* __restrict__ out_pc   = out + 3 * N;
    float* __restrict__ out_mask = out + 6 * N;

    const int tid    = blockIdx.x * blockDim.x + threadIdx.x;
    const int stride = gridDim.x * blockDim.x;

    for (int p = tid; p < n_pairs; p += stride) {
        const int pf = pair_first[p];
        const int ps = pair_second[p];
        const int s0 = shifts[3 * p + 0];
        const int s1 = shifts[3 * p + 1];
        const int s2 = shifts[3 * p + 2];

        const int ia = real_atoms[pf];
        const int ib = real_atoms[ps];

        const float ax = coords[3 * ia + 0];
        const float ay = coords[3 * ia + 1];
        const float az = coords[3 * ia + 2];
        const float bx = coords[3 * ib + 0];
        const float by = coords[3 * ib + 1];
        const float bz = coords[3 * ib + 2];

        const float f0 = (float)s0, f1 = (float)s1, f2 = (float)s2;
        // shifts @ cell : row-vector times row-major 3x3
        const float dx = bx - ax + f0 * c00 + f1 * c10 + f2 * c20;
        const float dy = by - ay + f0 * c01 + f1 * c11 + f2 * c21;
        const float dz = bz - az + f0 * c02 + f1 * c12 + f2 * c22;

        const float d = sqrtf(dx * dx + dy * dy + dz * dz);
        const bool  m = d < HARD_DIST_CUTOFF;

        out_dist[p] = m ? d : 0.0f;
        out_pf[p]   = m ? (float)pf : -1.0f;
        out_ps[p]   = m ? (float)ps : -1.0f;

        const size_t pc = 3 * (size_t)p;
        out_pc[pc + 0] = m ? dx : 0.0f;
        out_pc[pc + 1] = m ? dy : 0.0f;
        out_pc[pc + 2] = m ? dz : 0.0f;

        out_mask[p] = m ? 1.0f : 0.0f;
    }
}

extern "C" void kernel_launch(void* const* d_in, const int* in_sizes, int n_in,
                              void* d_out, int out_size, void* d_ws, size_t ws_size,
                              hipStream_t stream) {
    const float* coords      = (const float*)d_in[0];  // (128,1024,3) f32
    const int*   real_atoms  = (const int*)d_in[1];    // (131072,) int
    const int*   shifts      = (const int*)d_in[2];    // (8388608,3) int
    const float* cell        = (const float*)d_in[3];  // (3,3) f32
    const int*   pair_first  = (const int*)d_in[4];    // (8388608,) int
    const int*   pair_second = (const int*)d_in[5];    // (8388608,) int
    float*       out         = (float*)d_out;

    const int n_pairs = in_sizes[4];  // 8388608

    const int block = 256;
    const int grid  = 2048;  // grid-stride; memory-bound, ~16 pairs/thread

    external_neighbors_kernel<<<grid, block, 0, stream>>>(
        coords, real_atoms, shifts, cell, pair_first, pair_second, out, n_pairs);
}

// Round 3
// 481.000 us; speedup vs baseline: 1.0851x; 1.0851x over previous
//
#include <hip/hip_runtime.h>

// ExternalNeighbors: per-pair displacement + periodic shift + cutoff mask.
// Outputs (concatenated flat, all as float32):
//   [0*N .. 1*N) dist (0 if masked out)
//   [1*N .. 2*N) pair_first  (as float; -1 if masked out)
//   [2*N .. 3*N) pair_second (as float; -1 if masked out)
//   [3*N .. 6*N) paircoord (N,3) (0 if masked out)
//   [6*N .. 7*N) mask (1.0 / 0.0)
//
// Round-2 diagnosis: 270us @ 15% HBM, VALUBusy 5.7% -> latency-bound on the
// dependent gather chain (pair idx -> real_atoms -> coords), ~5 loads in
// flight. Fix: 4 pairs/thread, fully unrolled, vectorized index loads and
// stores -> ~35 independent loads in flight per thread.

#define HARD_DIST_CUTOFF 2.0f

__global__ __launch_bounds__(256) void external_neighbors_v2(
    const float* __restrict__ coords,       // n_real * 3
    const int*   __restrict__ real_atoms,   // n_real
    const int*   __restrict__ shifts,       // n_pairs * 3
    const float* __restrict__ cell,         // 9
    const int*   __restrict__ pair_first,   // n_pairs
    const int*   __restrict__ pair_second,  // n_pairs
    float* __restrict__ out,
    int n_pairs)
{
    const float c00 = cell[0], c01 = cell[1], c02 = cell[2];
    const float c10 = cell[3], c11 = cell[4], c12 = cell[5];
    const float c20 = cell[6], c21 = cell[7], c22 = cell[8];

    const size_t N = (size_t)n_pairs;
    float* __restrict__ out_dist = out;
    float* __restrict__ out_pf   = out + N;
    float* __restrict__ out_ps   = out + 2 * N;
    float* __restrict__ out_pc   = out + 3 * N;
    float* __restrict__ out_mask = out + 6 * N;

    const int tid  = blockIdx.x * blockDim.x + threadIdx.x;
    const int base = tid * 4;

    if (base + 3 < n_pairs) {
        // ---- vectorized index loads: 16B/lane, coalesced ----
        const int4 pf4 = *reinterpret_cast<const int4*>(pair_first  + base);
        const int4 ps4 = *reinterpret_cast<const int4*>(pair_second + base);
        // shifts: 12 ints per thread, 48B, 16B-aligned (48*tid % 16 == 0)
        const int4* sh = reinterpret_cast<const int4*>(shifts + 3 * base);
        const int4 sA = sh[0], sB = sh[1], sC = sh[2];

        const int pf[4] = {pf4.x, pf4.y, pf4.z, pf4.w};
        const int ps[4] = {ps4.x, ps4.y, ps4.z, ps4.w};
        const int s0[4] = {sA.x, sA.w, sB.z, sC.y};
        const int s1[4] = {sA.y, sB.x, sB.w, sC.z};
        const int s2[4] = {sA.z, sB.y, sC.x, sC.w};

        // ---- 8 independent real_atoms gathers (L2-resident table) ----
        int ia[4], ib[4];
        #pragma unroll
        for (int k = 0; k < 4; ++k) ia[k] = real_atoms[pf[k]];
        #pragma unroll
        for (int k = 0; k < 4; ++k) ib[k] = real_atoms[ps[k]];

        // ---- 24 independent coord loads ----
        float ax[4], ay[4], az[4], bx[4], by[4], bz[4];
        #pragma unroll
        for (int k = 0; k < 4; ++k) {
            const float* ca = coords + 3 * (size_t)ia[k];
            ax[k] = ca[0]; ay[k] = ca[1]; az[k] = ca[2];
        }
        #pragma unroll
        for (int k = 0; k < 4; ++k) {
            const float* cb = coords + 3 * (size_t)ib[k];
            bx[k] = cb[0]; by[k] = cb[1]; bz[k] = cb[2];
        }

        // ---- compute ----
        float4 dist, pfo, pso, msk;
        float dxv[4], dyv[4], dzv[4];
        float* distp = &dist.x; float* pfp = &pfo.x;
        float* psp = &pso.x;   float* mkp = &msk.x;
        #pragma unroll
        for (int k = 0; k < 4; ++k) {
            const float f0 = (float)s0[k], f1 = (float)s1[k], f2 = (float)s2[k];
            const float dx = bx[k] - ax[k] + f0 * c00 + f1 * c10 + f2 * c20;
            const float dy = by[k] - ay[k] + f0 * c01 + f1 * c11 + f2 * c21;
            const float dz = bz[k] - az[k] + f0 * c02 + f1 * c12 + f2 * c22;
            const float d  = sqrtf(dx * dx + dy * dy + dz * dz);
            const bool  m  = d < HARD_DIST_CUTOFF;
            distp[k] = m ? d : 0.0f;
            pfp[k]   = m ? (float)pf[k] : -1.0f;
            psp[k]   = m ? (float)ps[k] : -1.0f;
            mkp[k]   = m ? 1.0f : 0.0f;
            dxv[k]   = m ? dx : 0.0f;
            dyv[k]   = m ? dy : 0.0f;
            dzv[k]   = m ? dz : 0.0f;
        }

        // ---- vectorized stores ----
        *reinterpret_cast<float4*>(out_dist + base) = dist;
        *reinterpret_cast<float4*>(out_pf   + base) = pfo;
        *reinterpret_cast<float4*>(out_ps   + base) = pso;
        *reinterpret_cast<float4*>(out_mask + base) = msk;
        // paircoord: 12 floats, 48B, 16B-aligned
        float4* pc = reinterpret_cast<float4*>(out_pc + 3 * (size_t)base);
        pc[0] = make_float4(dxv[0], dyv[0], dzv[0], dxv[1]);
        pc[1] = make_float4(dyv[1], dzv[1], dxv[2], dyv[2]);
        pc[2] = make_float4(dzv[2], dxv[3], dyv[3], dzv[3]);
    } else {
        // tail (n_pairs % 4 != 0) — scalar fallback
        for (int p = base; p < n_pairs; ++p) {
            const int pfs = pair_first[p];
            const int pss = pair_second[p];
            const int t0 = shifts[3 * p + 0];
            const int t1 = shifts[3 * p + 1];
            const int t2 = shifts[3 * p + 2];
            const int iaa = real_atoms[pfs];
            const int ibb = real_atoms[pss];
            const float f0 = (float)t0, f1 = (float)t1, f2 = (float)t2;
            const float dx = coords[3*ibb+0] - coords[3*iaa+0] + f0*c00 + f1*c10 + f2*c20;
            const float dy = coords[3*ibb+1] - coords[3*iaa+1] + f0*c01 + f1*c11 + f2*c21;
            const float dz = coords[3*ibb+2] - coords[3*iaa+2] + f0*c02 + f1*c12 + f2*c22;
            const float d  = sqrtf(dx*dx + dy*dy + dz*dz);
            const bool  m  = d < HARD_DIST_CUTOFF;
            out_dist[p] = m ? d : 0.0f;
            out_pf[p]   = m ? (float)pfs : -1.0f;
            out_ps[p]   = m ? (float)pss : -1.0f;
            out_pc[3*(size_t)p+0] = m ? dx : 0.0f;
            out_pc[3*(size_t)p+1] = m ? dy : 0.0f;
            out_pc[3*(size_t)p+2] = m ? dz : 0.0f;
            out_mask[p] = m ? 1.0f : 0.0f;
        }
    }
}

extern "C" void kernel_launch(void* const* d_in, const int* in_sizes, int n_in,
                              void* d_out, int out_size, void* d_ws, size_t ws_size,
                              hipStream_t stream) {
    const float* coords      = (const float*)d_in[0];  // (128,1024,3) f32
    const int*   real_atoms  = (const int*)d_in[1];    // (131072,) int
    const int*   shifts      = (const int*)d_in[2];    // (8388608,3) int
    const float* cell        = (const float*)d_in[3];  // (3,3) f32
    const int*   pair_first  = (const int*)d_in[4];    // (8388608,) int
    const int*   pair_second = (const int*)d_in[5];    // (8388608,) int
    float*       out         = (float*)d_out;

    const int n_pairs = in_sizes[4];  // 8388608

    const int block = 256;
    const int pairs_per_thread = 4;
    const int grid = (n_pairs + block * pairs_per_thread - 1) / (block * pairs_per_thread);

    external_neighbors_v2<<<grid, block, 0, stream>>>(
        coords, real_atoms, shifts, cell, pair_first, pair_second, out, n_pairs);
}

// Round 4
// 440.042 us; speedup vs baseline: 1.1861x; 1.0931x over previous
//
#include <hip/hip_runtime.h>

// ExternalNeighbors: per-pair displacement + periodic shift + cutoff mask.
// Outputs (concatenated flat, all float32):
//   [0N..1N) dist | [1N..2N) pair_first | [2N..3N) pair_second
//   [3N..6N) paircoord (N,3) | [6N..7N) mask
//
// Round-3 diagnosis: 231us @ 18% HBM, VALUBusy 5.7% -> divergent-gather
// address-throughput bound (4 random loads/pair through a 2-hop chain).
// Fix: precompute tab[i] = coords[real_atoms[i]] (float4-padded, 2MB in
// d_ws) once per launch -> 2 single-line 16B gathers/pair, 1-hop chain.

#define HARD_DIST_CUTOFF 2.0f

__global__ __launch_bounds__(256) void build_gather_table(
    const float* __restrict__ coords,      // n_real * 3
    const int*   __restrict__ real_atoms,  // n_real
    float4* __restrict__ tab,              // n_real (padded xyz_)
    int n_real)
{
    const int i = blockIdx.x * blockDim.x + threadIdx.x;
    if (i < n_real) {
        const int a = real_atoms[i];
        const float* c = coords + 3 * (size_t)a;
        tab[i] = make_float4(c[0], c[1], c[2], 0.0f);
    }
}

__global__ __launch_bounds__(256) void external_neighbors_v3(
    const float4* __restrict__ tab,         // n_real, pre-gathered coords
    const int*    __restrict__ shifts,      // n_pairs * 3
    const float*  __restrict__ cell,        // 9
    const int*    __restrict__ pair_first,  // n_pairs
    const int*    __restrict__ pair_second, // n_pairs
    float* __restrict__ out,
    int n_pairs)
{
    const float c00 = cell[0], c01 = cell[1], c02 = cell[2];
    const float c10 = cell[3], c11 = cell[4], c12 = cell[5];
    const float c20 = cell[6], c21 = cell[7], c22 = cell[8];

    const size_t N = (size_t)n_pairs;
    float* __restrict__ out_dist = out;
    float* __restrict__ out_pf   = out + N;
    float* __restrict__ out_ps   = out + 2 * N;
    float* __restrict__ out_pc   = out + 3 * N;
    float* __restrict__ out_mask = out + 6 * N;

    const int tid  = blockIdx.x * blockDim.x + threadIdx.x;
    const int base = tid * 4;

    if (base + 3 < n_pairs) {
        const int4 pf4 = *reinterpret_cast<const int4*>(pair_first  + base);
        const int4 ps4 = *reinterpret_cast<const int4*>(pair_second + base);
        const int4* sh = reinterpret_cast<const int4*>(shifts + 3 * base);
        const int4 sA = sh[0], sB = sh[1], sC = sh[2];

        const int pf[4] = {pf4.x, pf4.y, pf4.z, pf4.w};
        const int ps[4] = {ps4.x, ps4.y, ps4.z, ps4.w};
        const int s0[4] = {sA.x, sA.w, sB.z, sC.y};
        const int s1[4] = {sA.y, sB.x, sB.w, sC.z};
        const int s2[4] = {sA.z, sB.y, sC.x, sC.w};

        // ---- 8 independent single-line 16B gathers (L2-resident table) ----
        float4 A[4], B[4];
        #pragma unroll
        for (int k = 0; k < 4; ++k) A[k] = tab[pf[k]];
        #pragma unroll
        for (int k = 0; k < 4; ++k) B[k] = tab[ps[k]];

        float4 dist, pfo, pso, msk;
        float dxv[4], dyv[4], dzv[4];
        float* distp = &dist.x; float* pfp = &pfo.x;
        float* psp = &pso.x;   float* mkp = &msk.x;
        #pragma unroll
        for (int k = 0; k < 4; ++k) {
            const float f0 = (float)s0[k], f1 = (float)s1[k], f2 = (float)s2[k];
            const float dx = B[k].x - A[k].x + f0 * c00 + f1 * c10 + f2 * c20;
            const float dy = B[k].y - A[k].y + f0 * c01 + f1 * c11 + f2 * c21;
            const float dz = B[k].z - A[k].z + f0 * c02 + f1 * c12 + f2 * c22;
            const float d  = sqrtf(dx * dx + dy * dy + dz * dz);
            const bool  m  = d < HARD_DIST_CUTOFF;
            distp[k] = m ? d : 0.0f;
            pfp[k]   = m ? (float)pf[k] : -1.0f;
            psp[k]   = m ? (float)ps[k] : -1.0f;
            mkp[k]   = m ? 1.0f : 0.0f;
            dxv[k]   = m ? dx : 0.0f;
            dyv[k]   = m ? dy : 0.0f;
            dzv[k]   = m ? dz : 0.0f;
        }

        *reinterpret_cast<float4*>(out_dist + base) = dist;
        *reinterpret_cast<float4*>(out_pf   + base) = pfo;
        *reinterpret_cast<float4*>(out_ps   + base) = pso;
        *reinterpret_cast<float4*>(out_mask + base) = msk;
        float4* pc = reinterpret_cast<float4*>(out_pc + 3 * (size_t)base);
        pc[0] = make_float4(dxv[0], dyv[0], dzv[0], dxv[1]);
        pc[1] = make_float4(dyv[1], dzv[1], dxv[2], dyv[2]);
        pc[2] = make_float4(dzv[2], dxv[3], dyv[3], dzv[3]);
    } else {
        for (int p = base; p < n_pairs; ++p) {
            const int pfs = pair_first[p];
            const int pss = pair_second[p];
            const float f0 = (float)shifts[3 * p + 0];
            const float f1 = (float)shifts[3 * p + 1];
            const float f2 = (float)shifts[3 * p + 2];
            const float4 Aa = tab[pfs];
            const float4 Bb = tab[pss];
            const float dx = Bb.x - Aa.x + f0 * c00 + f1 * c10 + f2 * c20;
            const float dy = Bb.y - Aa.y + f0 * c01 + f1 * c11 + f2 * c21;
            const float dz = Bb.z - Aa.z + f0 * c02 + f1 * c12 + f2 * c22;
            const float d  = sqrtf(dx * dx + dy * dy + dz * dz);
            const bool  m  = d < HARD_DIST_CUTOFF;
            out_dist[p] = m ? d : 0.0f;
            out_pf[p]   = m ? (float)pfs : -1.0f;
            out_ps[p]   = m ? (float)pss : -1.0f;
            out_pc[3*(size_t)p+0] = m ? dx : 0.0f;
            out_pc[3*(size_t)p+1] = m ? dy : 0.0f;
            out_pc[3*(size_t)p+2] = m ? dz : 0.0f;
            out_mask[p] = m ? 1.0f : 0.0f;
        }
    }
}

// Fallback (ws too small): round-3 two-hop kernel.
__global__ __launch_bounds__(256) void external_neighbors_v2(
    const float* __restrict__ coords,
    const int*   __restrict__ real_atoms,
    const int*   __restrict__ shifts,
    const float* __restrict__ cell,
    const int*   __restrict__ pair_first,
    const int*   __restrict__ pair_second,
    float* __restrict__ out,
    int n_pairs)
{
    const float c00 = cell[0], c01 = cell[1], c02 = cell[2];
    const float c10 = cell[3], c11 = cell[4], c12 = cell[5];
    const float c20 = cell[6], c21 = cell[7], c22 = cell[8];
    const size_t N = (size_t)n_pairs;
    float* out_dist = out;
    float* out_pf   = out + N;
    float* out_ps   = out + 2 * N;
    float* out_pc   = out + 3 * N;
    float* out_mask = out + 6 * N;
    const int tid = blockIdx.x * blockDim.x + threadIdx.x;
    const int stride = gridDim.x * blockDim.x;
    for (int p = tid; p < n_pairs; p += stride) {
        const int pfs = pair_first[p];
        const int pss = pair_second[p];
        const float f0 = (float)shifts[3 * p + 0];
        const float f1 = (float)shifts[3 * p + 1];
        const float f2 = (float)shifts[3 * p + 2];
        const int iaa = real_atoms[pfs];
        const int ibb = real_atoms[pss];
        const float dx = coords[3*ibb+0] - coords[3*iaa+0] + f0*c00 + f1*c10 + f2*c20;
        const float dy = coords[3*ibb+1] - coords[3*iaa+1] + f0*c01 + f1*c11 + f2*c21;
        const float dz = coords[3*ibb+2] - coords[3*iaa+2] + f0*c02 + f1*c12 + f2*c22;
        const float d  = sqrtf(dx*dx + dy*dy + dz*dz);
        const bool  m  = d < HARD_DIST_CUTOFF;
        out_dist[p] = m ? d : 0.0f;
        out_pf[p]   = m ? (float)pfs : -1.0f;
        out_ps[p]   = m ? (float)pss : -1.0f;
        out_pc[3*(size_t)p+0] = m ? dx : 0.0f;
        out_pc[3*(size_t)p+1] = m ? dy : 0.0f;
        out_pc[3*(size_t)p+2] = m ? dz : 0.0f;
        out_mask[p] = m ? 1.0f : 0.0f;
    }
}

extern "C" void kernel_launch(void* const* d_in, const int* in_sizes, int n_in,
                              void* d_out, int out_size, void* d_ws, size_t ws_size,
                              hipStream_t stream) {
    const float* coords      = (const float*)d_in[0];  // (128,1024,3) f32
    const int*   real_atoms  = (const int*)d_in[1];    // (131072,) int
    const int*   shifts      = (const int*)d_in[2];    // (8388608,3) int
    const float* cell        = (const float*)d_in[3];  // (3,3) f32
    const int*   pair_first  = (const int*)d_in[4];    // (8388608,) int
    const int*   pair_second = (const int*)d_in[5];    // (8388608,) int
    float*       out         = (float*)d_out;

    const int n_real  = in_sizes[1];  // 131072
    const int n_pairs = in_sizes[4];  // 8388608

    const size_t tab_bytes = (size_t)n_real * sizeof(float4);

    if (ws_size >= tab_bytes) {
        float4* tab = (float4*)d_ws;
        build_gather_table<<<(n_real + 255) / 256, 256, 0, stream>>>(
            coords, real_atoms, tab, n_real);

        const int block = 256;
        const int grid  = (n_pairs + block * 4 - 1) / (block * 4);
        external_neighbors_v3<<<grid, block, 0, stream>>>(
            tab, shifts, cell, pair_first, pair_second, out, n_pairs);
    } else {
        external_neighbors_v2<<<2048, 256, 0, stream>>>(
            coords, real_atoms, shifts, cell, pair_first, pair_second, out, n_pairs);
    }
}